// Round 5
// baseline (490.971 us; speedup 1.0000x reference)
//
#include <hip/hip_runtime.h>
#include <cfloat>

#define KC 512        // codes
#define DD 64         // dim
#define HW 4096       // 64*64
#define NPIX 131072   // 32*64*64
#define QSIZE 8388608 // 32*64*64*64
#define NBLK 512      // NPIX/256

// native vector type (first-class SSA value — no alloca, unlike float arrays,
// which the backend left in scratch: round-4 VGPR=48 + FETCH=17.3GB = xr[64]
// re-read from scratch per code)
typedef float nfloat4 __attribute__((ext_vector_type(4)));

__device__ __forceinline__ nfloat4 vsq(nfloat4 a) {
    return (nfloat4){__fmul_rn(a[0], a[0]), __fmul_rn(a[1], a[1]),
                     __fmul_rn(a[2], a[2]), __fmul_rn(a[3], a[3])};
}
__device__ __forceinline__ nfloat4 vadd(nfloat4 a, nfloat4 b) {
    return (nfloat4){__fadd_rn(a[0], b[0]), __fadd_rn(a[1], b[1]),
                     __fadd_rn(a[2], b[2]), __fadd_rn(a[3], b[3])};
}

// x held in 16 named vector registers
#define FOR16(M) M(0) M(1) M(2) M(3) M(4) M(5) M(6) M(7) \
                 M(8) M(9) M(10) M(11) M(12) M(13) M(14) M(15)

// ascending-d fp32 FMA chain, 4 elements of chunk c (d = 4c..4c+3)
#define DOT4(P, XC, WP, c) { \
    nfloat4 wv_ = *(const nfloat4*)((WP) + 4 * (c)); \
    P = __fmaf_rn(XC[0], wv_[0], P); \
    P = __fmaf_rn(XC[1], wv_[1], P); \
    P = __fmaf_rn(XC[2], wv_[2], P); \
    P = __fmaf_rn(XC[3], wv_[3], P); }

#define DOT64(P, WP) \
    DOT4(P, x0, WP, 0)  DOT4(P, x1, WP, 1)  DOT4(P, x2, WP, 2)  DOT4(P, x3, WP, 3) \
    DOT4(P, x4, WP, 4)  DOT4(P, x5, WP, 5)  DOT4(P, x6, WP, 6)  DOT4(P, x7, WP, 7) \
    DOT4(P, x8, WP, 8)  DOT4(P, x9, WP, 9)  DOT4(P, x10, WP, 10) DOT4(P, x11, WP, 11) \
    DOT4(P, x12, WP, 12) DOT4(P, x13, WP, 13) DOT4(P, x14, WP, 14) DOT4(P, x15, WP, 15)

// --- main: fp32-emulated argmin over 512 codes + quant + loss + one-hot enc
__global__ __launch_bounds__(256, 2) void vq_main(
    const float* __restrict__ x, const float* __restrict__ w,
    float* __restrict__ out_q, float* __restrict__ out_enc,
    float* __restrict__ out_idx, double* __restrict__ partial) {

    const int tid = threadIdx.x;
    const int n = blockIdx.x * 256 + tid;
    const int b = n >> 12;        // batch (4096 % 256 == 0, uniform per block)
    const int p = n & 4095;       // h*64+w

    // w2[k] = numpy-pairwise fp32 sum of w_kd^2, per block into LDS
    __shared__ float w2s[KC];
    for (int k = tid; k < KC; k += 256) {
        const float* wk = w + k * DD;
        float r0=0,r1=0,r2=0,r3=0,r4=0,r5=0,r6=0,r7=0;
        r0 = __fmul_rn(wk[0], wk[0]); r1 = __fmul_rn(wk[1], wk[1]);
        r2 = __fmul_rn(wk[2], wk[2]); r3 = __fmul_rn(wk[3], wk[3]);
        r4 = __fmul_rn(wk[4], wk[4]); r5 = __fmul_rn(wk[5], wk[5]);
        r6 = __fmul_rn(wk[6], wk[6]); r7 = __fmul_rn(wk[7], wk[7]);
        #pragma unroll
        for (int i = 8; i < DD; i += 8) {
            r0 = __fadd_rn(r0, __fmul_rn(wk[i+0], wk[i+0]));
            r1 = __fadd_rn(r1, __fmul_rn(wk[i+1], wk[i+1]));
            r2 = __fadd_rn(r2, __fmul_rn(wk[i+2], wk[i+2]));
            r3 = __fadd_rn(r3, __fmul_rn(wk[i+3], wk[i+3]));
            r4 = __fadd_rn(r4, __fmul_rn(wk[i+4], wk[i+4]));
            r5 = __fadd_rn(r5, __fmul_rn(wk[i+5], wk[i+5]));
            r6 = __fadd_rn(r6, __fmul_rn(wk[i+6], wk[i+6]));
            r7 = __fadd_rn(r7, __fmul_rn(wk[i+7], wk[i+7]));
        }
        w2s[k] = __fadd_rn(
            __fadd_rn(__fadd_rn(r0, r1), __fadd_rn(r2, r3)),
            __fadd_rn(__fadd_rn(r4, r5), __fadd_rn(r6, r7)));
    }

    // load this pixel's 64 channels into 16 named vector regs (coalesced)
    const float* xb = x + (size_t)b * DD * HW + p;
    #define DECLX(c) nfloat4 x##c = (nfloat4){ \
        xb[(size_t)(4*c+0)*HW], xb[(size_t)(4*c+1)*HW], \
        xb[(size_t)(4*c+2)*HW], xb[(size_t)(4*c+3)*HW]};
    FOR16(DECLX)

    // X = ||x||^2, numpy pairwise fp32: r[j] = sum_i a[8i+j] sequential,
    // then ((r0+r1)+(r2+r3))+((r4+r5)+(r6+r7)). e = r[0..3], o = r[4..7].
    nfloat4 e = vsq(x0), o = vsq(x1);
    e = vadd(e, vsq(x2));  o = vadd(o, vsq(x3));
    e = vadd(e, vsq(x4));  o = vadd(o, vsq(x5));
    e = vadd(e, vsq(x6));  o = vadd(o, vsq(x7));
    e = vadd(e, vsq(x8));  o = vadd(o, vsq(x9));
    e = vadd(e, vsq(x10)); o = vadd(o, vsq(x11));
    e = vadd(e, vsq(x12)); o = vadd(o, vsq(x13));
    e = vadd(e, vsq(x14)); o = vadd(o, vsq(x15));
    const float X = __fadd_rn(
        __fadd_rn(__fadd_rn(e[0], e[1]), __fadd_rn(e[2], e[3])),
        __fadd_rn(__fadd_rn(o[0], o[1]), __fadd_rn(o[2], o[3])));

    __syncthreads();   // w2s ready

    // argmin of fp32 dist_k = (X + w2_k) - 2*P_k, P_k = ascending-d fma chain
    // (BLAS per-element accumulation). Strict < = first-index tiebreak (np).
    // wk pointers are loop-uniform -> scalar s_load of w.
    float best = FLT_MAX;
    int bidx = 0;
    for (int k = 0; k < KC; k += 4) {
        const float* wk0 = w + (k + 0) * DD;
        const float* wk1 = w + (k + 1) * DD;
        const float* wk2 = w + (k + 2) * DD;
        const float* wk3 = w + (k + 3) * DD;
        float p0 = 0.f, p1 = 0.f, p2 = 0.f, p3 = 0.f;
        DOT64(p0, wk0)
        DOT64(p1, wk1)
        DOT64(p2, wk2)
        DOT64(p3, wk3)
        float d0 = __fsub_rn(__fadd_rn(X, w2s[k + 0]), __fadd_rn(p0, p0));
        float d1 = __fsub_rn(__fadd_rn(X, w2s[k + 1]), __fadd_rn(p1, p1));
        float d2 = __fsub_rn(__fadd_rn(X, w2s[k + 2]), __fadd_rn(p2, p2));
        float d3 = __fsub_rn(__fadd_rn(X, w2s[k + 3]), __fadd_rn(p3, p3));
        if (d0 < best) { best = d0; bidx = k + 0; }
        if (d1 < best) { best = d1; bidx = k + 1; }
        if (d2 < best) { best = d2; bidx = k + 2; }
        if (d3 < best) { best = d3; bidx = k + 3; }
    }

    out_idx[n] = (float)bidx;

    // quantized output (NCHW, same addressing as x) + local loss
    const float* wq = w + bidx * DD;    // per-lane gather, L2-resident (128 KB)
    float* qb = out_q + (size_t)b * DD * HW + p;
    float lsum = 0.f;
    #define QSTORE(c) { \
        nfloat4 qv = *(const nfloat4*)(wq + 4 * c); \
        nfloat4 dv = qv - x##c; \
        lsum = fmaf(dv[0], dv[0], lsum); lsum = fmaf(dv[1], dv[1], lsum); \
        lsum = fmaf(dv[2], dv[2], lsum); lsum = fmaf(dv[3], dv[3], lsum); \
        __builtin_nontemporal_store(qv[0], qb + (size_t)(4*c+0)*HW); \
        __builtin_nontemporal_store(qv[1], qb + (size_t)(4*c+1)*HW); \
        __builtin_nontemporal_store(qv[2], qb + (size_t)(4*c+2)*HW); \
        __builtin_nontemporal_store(qv[3], qb + (size_t)(4*c+3)*HW); }
    FOR16(QSTORE)

    // loss reduce: wave shuffle -> LDS -> one plain store per block
    #pragma unroll
    for (int off = 32; off > 0; off >>= 1)
        lsum += __shfl_down(lsum, off, 64);
    __shared__ float sred[4];
    if ((tid & 63) == 0) sred[tid >> 6] = lsum;
    __syncthreads();
    if (tid == 0)
        partial[blockIdx.x] = (double)sred[0] + (double)sred[1]
                            + (double)sred[2] + (double)sred[3];

    // one-hot enc rows for this block's 256 pixels (512 KB, nontemporal)
    __shared__ int sidx[256];
    sidx[tid] = bidx;
    __syncthreads();

    // enc base byte-address == 4 (mod 16): 3-float head, aligned body, 1 tail
    float* basep = out_enc + (size_t)blockIdx.x * (256 * KC);
    for (int t = tid; t < 32767; t += 256) {
        int u = 3 + 4 * t;
        nfloat4 v;
        #pragma unroll
        for (int j = 0; j < 4; ++j) {
            int ei = u + j;
            int row = ei >> 9;          // pixel within block
            int col = ei & (KC - 1);
            v[j] = (sidx[row] == col) ? 1.0f : 0.0f;
        }
        __builtin_nontemporal_store(v, (nfloat4*)(basep + u));
    }
    if (tid < 3) basep[tid] = (sidx[0] == tid) ? 1.0f : 0.0f;
    else if (tid == 3) basep[131071] = (sidx[255] == 511) ? 1.0f : 0.0f;
}

// --- epilogue: loss = vq + commit = 2 * mean((q - x)^2)
__global__ void finish_kernel(const double* __restrict__ partial,
                              float* __restrict__ out) {
    int t = threadIdx.x;                 // 256 threads, 512 partials
    double s = partial[t] + partial[t + 256];
    #pragma unroll
    for (int off = 32; off > 0; off >>= 1)
        s += __shfl_down(s, off, 64);
    __shared__ double sr[4];
    if ((t & 63) == 0) sr[t >> 6] = s;
    __syncthreads();
    if (t == 0)
        out[0] = (float)(2.0 * (sr[0] + sr[1] + sr[2] + sr[3]) / (double)QSIZE);
}

extern "C" void kernel_launch(void* const* d_in, const int* in_sizes, int n_in,
                              void* d_out, int out_size, void* d_ws, size_t ws_size,
                              hipStream_t stream) {
    const float* x = (const float*)d_in[0];   // [32,64,64,64] f32 NCHW
    const float* w = (const float*)d_in[1];   // [512,64] f32
    float* out = (float*)d_out;
    float* out_q = out + 1;
    float* out_enc = out_q + QSIZE;
    float* out_idx = out_enc + (size_t)NPIX * KC;

    double* partial = (double*)d_ws;          // 512 doubles = 4 KB

    vq_main<<<NBLK, 256, 0, stream>>>(x, w, out_q, out_enc, out_idx, partial);
    finish_kernel<<<1, 256, 0, stream>>>(partial, out);
}

// Round 6
// 440.936 us; speedup vs baseline: 1.1135x; 1.1135x over previous
//
#include <hip/hip_runtime.h>
#include <cfloat>

#define KC 512        // codes
#define DD 64         // dim
#define HW 4096       // 64*64
#define NPIX 131072   // 32*64*64
#define QSIZE 8388608 // 32*64*64*64
#define PXB 128       // pixels per block
#define NBLK (NPIX / PXB)  // 1024
#define NTH 512       // 8 waves
#define MARGIN 4.0e-3f  // >6x worst-case screen-vs-np error bound

typedef short short8 __attribute__((ext_vector_type(8)));   // 8 bf16 (guide-verified MFMA operand)
typedef float f32x4 __attribute__((ext_vector_type(4)));
typedef float nfloat4 __attribute__((ext_vector_type(4)));
typedef unsigned long long u64;

__device__ __forceinline__ unsigned short bf16_rne(float f) {
    unsigned int u = __float_as_uint(f);
    u += 0x7FFFu + ((u >> 16) & 1u);
    return (unsigned short)(u >> 16);
}

// Block: 128 pixels x all 512 codes. Screen distances via bf16 MFMA
// (S = w2 + (-2x).w accumulated fp32), refine candidates with the bit-exact
// numpy fp32 formula (validated rounds 2-5), then write all four outputs.
__global__ __launch_bounds__(NTH, 2) void vq_fused(
    const float* __restrict__ x, const float* __restrict__ w,
    float* __restrict__ out_q, float* __restrict__ out_enc,
    float* __restrict__ out_idx, double* __restrict__ partial) {

  __shared__ uint4 wlds[4096];        // 64 KB: B-frags pre-swizzled, slot=(ct*2+kc)*64+lane
  __shared__ float xlds[PXB * 65];    // x tile fp32, row stride 65 (bank-conflict-free)
  __shared__ float w2s[KC];           // np-exact ||w_k||^2
  __shared__ u64 candm[PXB][8];       // 512-bit candidate mask per pixel
  __shared__ float Xs[PXB];           // np-exact ||x||^2 per pixel
  __shared__ int sidx[PXB];
  __shared__ float sredf[8];

  const int tid = threadIdx.x;
  const int lane = tid & 63;
  const int wv = tid >> 6;            // wave 0..7, each owns 16 pixels
  const int bix = blockIdx.x;
  const int b = bix >> 5;             // 32 blocks per image (4096/128)
  const int p0 = (bix & 31) * PXB;
  const float* xg = x + (size_t)b * (DD * HW) + p0;

  // ---- stage x tile (coalesced 256B rows) ----
  for (int i = tid; i < PXB * DD; i += NTH) {
    int d = i >> 7, pp = i & 127;
    xlds[pp * 65 + d] = xg[(size_t)d * HW + pp];
  }

  // ---- w2s: np-pairwise fp32, one code per thread (KC==NTH) ----
  {
    const int k = tid;
    const float* wk = w + k * DD;
    float r0 = __fmul_rn(wk[0], wk[0]), r1 = __fmul_rn(wk[1], wk[1]),
          r2 = __fmul_rn(wk[2], wk[2]), r3 = __fmul_rn(wk[3], wk[3]),
          r4 = __fmul_rn(wk[4], wk[4]), r5 = __fmul_rn(wk[5], wk[5]),
          r6 = __fmul_rn(wk[6], wk[6]), r7 = __fmul_rn(wk[7], wk[7]);
    #pragma unroll
    for (int i = 8; i < DD; i += 8) {
      r0 = __fadd_rn(r0, __fmul_rn(wk[i+0], wk[i+0]));
      r1 = __fadd_rn(r1, __fmul_rn(wk[i+1], wk[i+1]));
      r2 = __fadd_rn(r2, __fmul_rn(wk[i+2], wk[i+2]));
      r3 = __fadd_rn(r3, __fmul_rn(wk[i+3], wk[i+3]));
      r4 = __fadd_rn(r4, __fmul_rn(wk[i+4], wk[i+4]));
      r5 = __fadd_rn(r5, __fmul_rn(wk[i+5], wk[i+5]));
      r6 = __fadd_rn(r6, __fmul_rn(wk[i+6], wk[i+6]));
      r7 = __fadd_rn(r7, __fmul_rn(wk[i+7], wk[i+7]));
    }
    w2s[k] = __fadd_rn(__fadd_rn(__fadd_rn(r0, r1), __fadd_rn(r2, r3)),
                       __fadd_rn(__fadd_rn(r4, r5), __fadd_rn(r6, r7)));
  }

  // ---- stage w as bf16 B-frags: slot lane holds w[ct*16+n][kc*32+q*8+j] ----
  for (int s = tid; s < 4096; s += NTH) {
    int ct = s >> 7, kc = (s >> 6) & 1, ln = s & 63;
    int n = ln & 15, q = ln >> 4;
    const float* wp = w + (ct * 16 + n) * DD + kc * 32 + q * 8;
    nfloat4 f0 = *(const nfloat4*)(wp);
    nfloat4 f1 = *(const nfloat4*)(wp + 4);
    uint4 u;
    u.x = (unsigned)bf16_rne(f0[0]) | ((unsigned)bf16_rne(f0[1]) << 16);
    u.y = (unsigned)bf16_rne(f0[2]) | ((unsigned)bf16_rne(f0[3]) << 16);
    u.z = (unsigned)bf16_rne(f1[0]) | ((unsigned)bf16_rne(f1[1]) << 16);
    u.w = (unsigned)bf16_rne(f1[2]) | ((unsigned)bf16_rne(f1[3]) << 16);
    wlds[s] = u;
  }
  for (int i = tid; i < PXB * 8; i += NTH) ((u64*)candm)[i] = 0;
  __syncthreads();

  // ---- Xs: np-pairwise ||x||^2, one pixel per thread (waves 0-1) ----
  if (tid < PXB) {
    const float* xr = &xlds[tid * 65];
    float r0 = __fmul_rn(xr[0], xr[0]), r1 = __fmul_rn(xr[1], xr[1]),
          r2 = __fmul_rn(xr[2], xr[2]), r3 = __fmul_rn(xr[3], xr[3]),
          r4 = __fmul_rn(xr[4], xr[4]), r5 = __fmul_rn(xr[5], xr[5]),
          r6 = __fmul_rn(xr[6], xr[6]), r7 = __fmul_rn(xr[7], xr[7]);
    #pragma unroll
    for (int i = 8; i < DD; i += 8) {
      r0 = __fadd_rn(r0, __fmul_rn(xr[i+0], xr[i+0]));
      r1 = __fadd_rn(r1, __fmul_rn(xr[i+1], xr[i+1]));
      r2 = __fadd_rn(r2, __fmul_rn(xr[i+2], xr[i+2]));
      r3 = __fadd_rn(r3, __fmul_rn(xr[i+3], xr[i+3]));
      r4 = __fadd_rn(r4, __fmul_rn(xr[i+4], xr[i+4]));
      r5 = __fadd_rn(r5, __fmul_rn(xr[i+5], xr[i+5]));
      r6 = __fadd_rn(r6, __fmul_rn(xr[i+6], xr[i+6]));
      r7 = __fadd_rn(r7, __fmul_rn(xr[i+7], xr[i+7]));
    }
    Xs[tid] = __fadd_rn(__fadd_rn(__fadd_rn(r0, r1), __fadd_rn(r2, r3)),
                        __fadd_rn(__fadd_rn(r4, r5), __fadd_rn(r6, r7)));
  }

  // ---- A-frags: A[m=lane&15][k=quad*8+j] of (-2x) in bf16 (exact x-2) ----
  const int am = lane & 15, aq = lane >> 4;
  const float* arow = &xlds[(wv * 16 + am) * 65];
  short8 a0, a1;
  #pragma unroll
  for (int j = 0; j < 8; ++j) {
    a0[j] = (short)bf16_rne(-2.0f * arow[aq * 8 + j]);
    a1[j] = (short)bf16_rne(-2.0f * arow[32 + aq * 8 + j]);
  }

  const short8* wl8 = (const short8*)wlds;
  const int cn = lane & 15;   // C-layout col (code within tile)

  // ---- pass 1: per-pixel min of screened S over 512 codes ----
  // C layout (m89-verified): col=lane&15, row=(lane>>4)*4+reg
  float m0 = FLT_MAX, m1 = FLT_MAX, m2 = FLT_MAX, m3 = FLT_MAX;
  for (int ct = 0; ct < 32; ++ct) {
    float wk2 = w2s[ct * 16 + cn];
    f32x4 acc = {wk2, wk2, wk2, wk2};
    acc = __builtin_amdgcn_mfma_f32_16x16x32_bf16(a0, wl8[ct * 128 + lane], acc, 0, 0, 0);
    acc = __builtin_amdgcn_mfma_f32_16x16x32_bf16(a1, wl8[ct * 128 + 64 + lane], acc, 0, 0, 0);
    m0 = fminf(m0, acc[0]); m1 = fminf(m1, acc[1]);
    m2 = fminf(m2, acc[2]); m3 = fminf(m3, acc[3]);
  }
  #pragma unroll
  for (int s = 1; s < 16; s <<= 1) {   // reduce across the 16 lanes of each quad
    m0 = fminf(m0, __shfl_xor(m0, s));
    m1 = fminf(m1, __shfl_xor(m1, s));
    m2 = fminf(m2, __shfl_xor(m2, s));
    m3 = fminf(m3, __shfl_xor(m3, s));
  }
  const float t0 = m0 + MARGIN, t1 = m1 + MARGIN,
              t2 = m2 + MARGIN, t3 = m3 + MARGIN;

  // ---- pass 2: flag candidates into per-pixel bitmasks ----
  for (int ct = 0; ct < 32; ++ct) {
    float wk2 = w2s[ct * 16 + cn];
    f32x4 acc = {wk2, wk2, wk2, wk2};
    acc = __builtin_amdgcn_mfma_f32_16x16x32_bf16(a0, wl8[ct * 128 + lane], acc, 0, 0, 0);
    acc = __builtin_amdgcn_mfma_f32_16x16x32_bf16(a1, wl8[ct * 128 + 64 + lane], acc, 0, 0, 0);
    u64 bm0 = __ballot(acc[0] <= t0);
    u64 bm1 = __ballot(acc[1] <= t1);
    u64 bm2 = __ballot(acc[2] <= t2);
    u64 bm3 = __ballot(acc[3] <= t3);
    if (lane < 4) {     // lane r owns reg r; ballot bit (q*16+n) -> pixel q*4+r, code ct*16+n
      u64 mk = (lane == 0) ? bm0 : (lane == 1) ? bm1 : (lane == 2) ? bm2 : bm3;
      int word = ct >> 2, sh = (ct & 3) * 16;
      #pragma unroll
      for (int q = 0; q < 4; ++q) {
        u64 bits = (mk >> (q * 16)) & 0xFFFFull;
        if (bits) candm[wv * 16 + q * 4 + lane][word] |= bits << sh;
      }
    }
  }
  __syncthreads();

  // ---- refine: 4 threads per pixel, exact np fp32 dist over candidates ----
  {
    const int px = tid >> 2, part = tid & 3;
    const float X = Xs[px];
    const float* xr = &xlds[px * 65];
    float bestd = FLT_MAX; int bk = 1 << 30;
    for (int wd = part * 2; wd < part * 2 + 2; ++wd) {
      u64 msk = candm[px][wd];
      while (msk) {
        int bit = __ffsll((unsigned long long)msk) - 1;
        msk &= msk - 1;
        int k = wd * 64 + bit;
        const float* wp = w + k * DD;
        float P = 0.f;                       // ascending-d fma chain (BLAS order)
        #pragma unroll
        for (int dc = 0; dc < 16; ++dc) {
          nfloat4 w4 = *(const nfloat4*)(wp + dc * 4);
          P = __fmaf_rn(xr[dc * 4 + 0], w4[0], P);
          P = __fmaf_rn(xr[dc * 4 + 1], w4[1], P);
          P = __fmaf_rn(xr[dc * 4 + 2], w4[2], P);
          P = __fmaf_rn(xr[dc * 4 + 3], w4[3], P);
        }
        float dist = __fsub_rn(__fadd_rn(X, w2s[k]), __fadd_rn(P, P));
        if (dist < bestd || (dist == bestd && k < bk)) { bestd = dist; bk = k; }
      }
    }
    // merge the 4 parts (tie -> smaller k, matching np.argmin first-index)
    float od = __shfl_down(bestd, 1); int ok = __shfl_down(bk, 1);
    if ((lane & 3) < 3 && (od < bestd || (od == bestd && ok < bk))) { bestd = od; bk = ok; }
    od = __shfl_down(bestd, 2); ok = __shfl_down(bk, 2);
    if ((lane & 3) < 2 && (od < bestd || (od == bestd && ok < bk))) { bestd = od; bk = ok; }
    if (part == 0) { sidx[px] = bk; out_idx[bix * PXB + px] = (float)bk; }
  }
  __syncthreads();

  // ---- quant (coalesced 256B rows) + loss ----
  float lsum = 0.f;
  float* qb = out_q + (size_t)b * (DD * HW) + p0;
  for (int i = tid; i < PXB * DD; i += NTH) {
    int d = i >> 7, pp = i & 127;
    float qv = w[sidx[pp] * DD + d];      // L1/L2-resident gather
    float dv = qv - xlds[pp * 65 + d];
    lsum = __fmaf_rn(dv, dv, lsum);
    __builtin_nontemporal_store(qv, qb + (size_t)d * HW + pp);
  }
  #pragma unroll
  for (int off = 32; off > 0; off >>= 1) lsum += __shfl_down(lsum, off);
  if (lane == 0) sredf[wv] = lsum;
  __syncthreads();
  if (tid == 0) {
    double t = 0.0;
    #pragma unroll
    for (int i = 0; i < 8; ++i) t += (double)sredf[i];
    partial[bix] = t;
  }

  // ---- one-hot enc (base ≡ 1 mod 4 floats: 3-head, aligned body, 1-tail) ----
  float* basep = out_enc + (size_t)bix * (PXB * KC);
  for (int t = tid; t < 16383; t += NTH) {
    int u = 3 + 4 * t;
    nfloat4 v;
    #pragma unroll
    for (int j = 0; j < 4; ++j) {
      int e = u + j;
      v[j] = (sidx[e >> 9] == (e & 511)) ? 1.0f : 0.0f;
    }
    __builtin_nontemporal_store(v, (nfloat4*)(basep + u));
  }
  if (tid < 3) basep[tid] = (sidx[0] == tid) ? 1.0f : 0.0f;
  else if (tid == 3) basep[PXB * KC - 1] = (sidx[127] == 511) ? 1.0f : 0.0f;
}

// --- epilogue: loss = vq + commit = 2 * mean((q - x)^2) ---
__global__ void finish_kernel(const double* __restrict__ partial,
                              float* __restrict__ out) {
  int t = threadIdx.x;   // 256 threads, 1024 partials
  double s = partial[t] + partial[t + 256] + partial[t + 512] + partial[t + 768];
  #pragma unroll
  for (int off = 32; off > 0; off >>= 1) s += __shfl_down(s, off);
  __shared__ double sr[4];
  if ((t & 63) == 0) sr[t >> 6] = s;
  __syncthreads();
  if (t == 0)
    out[0] = (float)(2.0 * (sr[0] + sr[1] + sr[2] + sr[3]) / (double)QSIZE);
}

extern "C" void kernel_launch(void* const* d_in, const int* in_sizes, int n_in,
                              void* d_out, int out_size, void* d_ws, size_t ws_size,
                              hipStream_t stream) {
  const float* x = (const float*)d_in[0];   // [32,64,64,64] f32 NCHW
  const float* w = (const float*)d_in[1];   // [512,64] f32
  float* out = (float*)d_out;
  float* out_q = out + 1;
  float* out_enc = out_q + QSIZE;
  float* out_idx = out_enc + (size_t)NPIX * KC;

  double* partial = (double*)d_ws;          // 1024 doubles = 8 KB

  vq_fused<<<NBLK, NTH, 0, stream>>>(x, w, out_q, out_enc, out_idx, partial);
  finish_kernel<<<1, 256, 0, stream>>>(partial, out);
}